// Round 4
// baseline (492.486 us; speedup 1.0000x reference)
//
#include <hip/hip_runtime.h>
#include <hip/hip_bf16.h>

typedef __attribute__((ext_vector_type(8))) short bf16x8;
typedef __attribute__((ext_vector_type(4))) float f32x4;

#define HID 512
#define NB 32
#define SEQL 4096
#define BM 64
#define NKC 16          // 512/32 k-chunks
#define NBLK 2048       // 131072 rows / 64
#define APAD 8
#define AW (HID + APAD) // 520 shorts: row stride 1040 B = 65x16 B (odd) -> 2-way max on b128 reads (free, m136)

// workspace layout (bytes)
#define WS_BP    0              // packed bf16 W_enc: 512 KB
#define WS_DPROJ (512*1024)     // fp32 32x512: 64 KB
#define WS_SUM   (576*1024)     // fp32 32: 128 B

__device__ __forceinline__ short f2bf(float f) {
    unsigned u = __float_as_uint(f);
    unsigned r = (u + 0x7fffu + ((u >> 16) & 1u)) >> 16;   // RNE
    return (short)r;
}

__device__ __forceinline__ float fast_tanh(float x) {
    float e = __expf(2.0f * x);
    float r = __builtin_amdgcn_rcpf(e + 1.0f);
    return 1.0f - 2.0f * r;
}

// ---------------------------------------------------------------------------
// K_pre: (a) W_enc pack fp32->bf16 B-frag layout [blk 0..127],
// (b) dproj GEMV, 8-way h-parallel [blk 128..639], (c) zero-init [blk 640..703]
// ---------------------------------------------------------------------------
__global__ void k_pre(const float* __restrict__ We, short* __restrict__ Bp,
                      const float* __restrict__ dec, const float* __restrict__ Wd,
                      const float* __restrict__ be, const float* __restrict__ bd,
                      float* __restrict__ dproj, float* __restrict__ out,
                      float* __restrict__ sumacc) {
    const int blk = blockIdx.x, t = threadIdx.x;
    if (blk < 128) {
        // Bp[kc][nt][lane][j] = We[kc*32 + (lane>>4)*8 + j][nt*16 + (lane&15)]
        int tid  = blk * 256 + t;
        int lane = tid & 63;
        int nt   = (tid >> 6) & 31;
        int kc   = tid >> 11;
        int k0   = kc * 32 + (lane >> 4) * 8;
        int n    = nt * 16 + (lane & 15);
        bf16x8 v;
#pragma unroll
        for (int j = 0; j < 8; ++j) v[j] = f2bf(We[(size_t)(k0 + j) * HID + n]);
        *(bf16x8*)&Bp[(size_t)tid * 8] = v;
    } else if (blk < 640) {
        __shared__ float red[8][33];
        int bid2 = blk - 128;
        int b  = bid2 >> 4, kg = bid2 & 15;     // 32 batches x 16 k-groups
        int kl = t & 31,    hc = t >> 5;        // 32 k-cols x 8 h-chunks
        int k  = kg * 32 + kl;
        const float* dr = dec + (size_t)b * HID;
        float a = 0.f;
#pragma unroll 8
        for (int j = 0; j < 64; ++j) {
            int h = hc * 64 + j;
            a += dr[h] * Wd[(size_t)h * HID + k];
        }
        red[hc][kl] = a;
        __syncthreads();
        if (hc == 0) {
            float s = be[k] + bd[k];
#pragma unroll
            for (int c = 0; c < 8; ++c) s += red[c][kl];
            dproj[(size_t)b * HID + k] = s;
        }
    } else {
        int bz = blk - 640;
        out[bz * 256 + t] = 0.f;                // zero context region
        if (bz == 0 && t < NB) sumacc[t] = 0.f;
    }
}

// ---------------------------------------------------------------------------
// K_main: barrier-free K-loop.
//  - Whole 64x512 A-tile staged to LDS as bf16 ONCE (single __syncthreads).
//  - B fragments read straight from L2-resident Bp into VGPRs (coalesced 16B),
//    register-double-buffered: loads for kc+1 in flight under the 32 MFMAs of
//    kc with fine-grained vmcnt — no vmcnt(0) barrier drain anywhere in loop.
//  - Fused tanh*W_v -> score -> exp -> partial expsum + partial context.
// ---------------------------------------------------------------------------
__global__ __launch_bounds__(256, 2)
void k_main(const float* __restrict__ E, const short* __restrict__ Bp,
            const float* __restrict__ dproj, const float* __restrict__ Wv,
            float* __restrict__ out, float* __restrict__ sumacc) {
    __shared__ short As[BM][AW];     // 66.5 KB
    __shared__ float fbuf[640];
    __shared__ float pbuf[BM];

    const int tid  = threadIdx.x;
    const int wave = tid >> 6, lane = tid & 63;
    const int quad = lane >> 4, l15 = lane & 15;
    const int bid  = blockIdx.x;
    const int row0 = bid * BM;           // global row = b*4096 + s
    const int b    = bid >> 6;           // 64 blocks per batch

    f32x4 acc[4][8];
#pragma unroll
    for (int r = 0; r < 4; ++r)
#pragma unroll
        for (int c = 0; c < 8; ++c) acc[r][c] = (f32x4){0.f, 0.f, 0.f, 0.f};

    // ---- stage full A-tile: flat-contiguous loads (4 KB / wave-issue) ----
    // iter i: thread t loads float4 #(i*256+t) of the 64x512 tile.
    // row = 2i + (t>>7), col = (t&127)*4 -> ds_write_b64, conflict-free.
    const float4* E4 = (const float4*)E + (size_t)row0 * (HID / 4);
    const int drow = tid >> 7;
    const int dcol = (tid & 127) * 4;
#pragma unroll
    for (int ph = 0; ph < 4; ++ph) {
        float4 v[8];
#pragma unroll
        for (int j = 0; j < 8; ++j)
            v[j] = E4[(size_t)(ph * 8 + j) * 256 + tid];
#pragma unroll
        for (int j = 0; j < 8; ++j) {
            int row = (ph * 8 + j) * 2 + drow;
            short4 s;
            s.x = f2bf(v[j].x); s.y = f2bf(v[j].y);
            s.z = f2bf(v[j].z); s.w = f2bf(v[j].w);
            *(short4*)&As[row][dcol] = s;
        }
    }

    // ---- preload B frags for kc=0 (global, no LDS dependency) ----
    const short* bbase = Bp + ((size_t)(wave * 8) * 64 + lane) * 8;
    bf16x8 fb[2][4][2];   // [buf][c-pair][..] flattened as [buf][c]
    bf16x8 fbr[2][8];
#pragma unroll
    for (int c = 0; c < 8; ++c)
        fbr[0][c] = *(const bf16x8*)(bbase + (size_t)c * 64 * 8);

    __syncthreads();   // the ONLY barrier before the epilogue

    bf16x8 fa[2][4];
#pragma unroll
    for (int r = 0; r < 4; ++r)
        fa[0][r] = *(const bf16x8*)&As[r * 16 + l15][quad * 8];

    // ---- barrier-free K-loop, register-double-buffered frags ----
#pragma unroll
    for (int kc = 0; kc < NKC; ++kc) {
        const int cur = kc & 1, nxt = cur ^ 1;
        if (kc + 1 < NKC) {
#pragma unroll
            for (int c = 0; c < 8; ++c)
                fbr[nxt][c] = *(const bf16x8*)(bbase + ((size_t)(kc + 1) * 2048 + c * 64) * 8);
#pragma unroll
            for (int r = 0; r < 4; ++r)
                fa[nxt][r] = *(const bf16x8*)&As[r * 16 + l15][(kc + 1) * 32 + quad * 8];
        }
#pragma unroll
        for (int c = 0; c < 8; ++c)
#pragma unroll
            for (int r = 0; r < 4; ++r)
                acc[r][c] = __builtin_amdgcn_mfma_f32_16x16x32_bf16(fa[cur][r], fbr[cur][c], acc[r][c], 0, 0, 0);
    }

    // ---- epilogue a: score = sum_col tanh(acc + dproj[col]) * Wv[col] ----
    float part[4][4];
#pragma unroll
    for (int r = 0; r < 4; ++r)
#pragma unroll
        for (int g = 0; g < 4; ++g) part[r][g] = 0.f;
    const float* dp = dproj + (size_t)b * HID;
#pragma unroll
    for (int c = 0; c < 8; ++c) {
        int col = wave * 128 + c * 16 + l15;
        float dv = dp[col];
        float wv = Wv[col];
#pragma unroll
        for (int r = 0; r < 4; ++r)
#pragma unroll
            for (int g = 0; g < 4; ++g)
                part[r][g] += fast_tanh(acc[r][c][g] + dv) * wv;
    }
#pragma unroll
    for (int r = 0; r < 4; ++r)
#pragma unroll
        for (int g = 0; g < 4; ++g) {
            float v = part[r][g];
            v += __shfl_xor(v, 1); v += __shfl_xor(v, 2);
            v += __shfl_xor(v, 4); v += __shfl_xor(v, 8);
            part[r][g] = v;
        }
    if (l15 == 0) {
#pragma unroll
        for (int r = 0; r < 4; ++r)
#pragma unroll
            for (int g = 0; g < 4; ++g)
                fbuf[wave * 64 + r * 16 + quad * 4 + g] = part[r][g];
    }
    __syncthreads();
    if (tid < 64) {
        float s  = fbuf[tid] + fbuf[64 + tid] + fbuf[128 + tid] + fbuf[192 + tid];
        float pv = __expf(s);           // unnormalized; b_v cancels in softmax
        pbuf[tid] = pv;
        out[(size_t)NB * HID + row0 + tid] = pv;
        float t2 = pv;
        t2 += __shfl_xor(t2, 1);  t2 += __shfl_xor(t2, 2);  t2 += __shfl_xor(t2, 4);
        t2 += __shfl_xor(t2, 8);  t2 += __shfl_xor(t2, 16); t2 += __shfl_xor(t2, 32);
        if (tid == 0) atomicAdd(&sumacc[b], t2);
    }
    __syncthreads();

    // ---- epilogue b: partial context = sum_rows pv * E[row,:] (L2/L3-hot) ----
    const int hq = tid & 127, rh = tid >> 7;
    const float4* Eb = (const float4*)E;
    size_t cbase = (size_t)(row0 + rh * 32) * (HID / 4) + hq;
    float4 ca = {0.f, 0.f, 0.f, 0.f};
#pragma unroll 4
    for (int rr = 0; rr < 32; ++rr) {
        float w  = pbuf[rh * 32 + rr];
        float4 e = Eb[cbase + (size_t)rr * (HID / 4)];
        ca.x += w * e.x; ca.y += w * e.y; ca.z += w * e.z; ca.w += w * e.w;
    }
    if (rh == 1) {
        fbuf[hq] = ca.x; fbuf[128 + hq] = ca.y; fbuf[256 + hq] = ca.z; fbuf[384 + hq] = ca.w;
    }
    __syncthreads();
    if (rh == 0) {
        ca.x += fbuf[hq]; ca.y += fbuf[128 + hq]; ca.z += fbuf[256 + hq]; ca.w += fbuf[384 + hq];
        float* cg = out + (size_t)b * HID + hq * 4;
        atomicAdd(cg + 0, ca.x); atomicAdd(cg + 1, ca.y);
        atomicAdd(cg + 2, ca.z); atomicAdd(cg + 3, ca.w);
    }
}

// ---------------------------------------------------------------------------
// K_finish: normalize in place: context /= sum, weights /= sum
// ---------------------------------------------------------------------------
__global__ void k_finish(float* __restrict__ out, const float* __restrict__ sumacc) {
    int b = blockIdx.x, t = threadIdx.x;
    float rs = 1.0f / sumacc[b];
    for (int i = t; i < HID; i += 256)
        out[(size_t)b * HID + i] *= rs;
    float* ow = out + (size_t)NB * HID + (size_t)b * SEQL;
    for (int i = t; i < SEQL; i += 256)
        ow[i] *= rs;
}

extern "C" void kernel_launch(void* const* d_in, const int* in_sizes, int n_in,
                              void* d_out, int out_size, void* d_ws, size_t ws_size,
                              hipStream_t stream) {
    const float* E   = (const float*)d_in[0];
    const float* dec = (const float*)d_in[1];
    const float* We  = (const float*)d_in[2];
    const float* be  = (const float*)d_in[3];
    const float* Wd  = (const float*)d_in[4];
    const float* bd  = (const float*)d_in[5];
    const float* Wv  = (const float*)d_in[6];
    // d_in[7] = b_v: uniform shift per score -> cancels in softmax
    float* out = (float*)d_out;
    char*  ws  = (char*)d_ws;
    short* Bp     = (short*)(ws + WS_BP);
    float* dproj  = (float*)(ws + WS_DPROJ);
    float* sumacc = (float*)(ws + WS_SUM);

    k_pre<<<704, 256, 0, stream>>>(We, Bp, dec, Wd, be, bd, dproj, out, sumacc);
    k_main<<<NBLK, 256, 0, stream>>>(E, Bp, dproj, Wv, out, sumacc);
    k_finish<<<NB, 256, 0, stream>>>(out, sumacc);
}